// Round 1
// baseline (7265.215 us; speedup 1.0000x reference)
//
// ATTPredictor on MI355X — round 0: complete correctness-first implementation.
//
// Pipeline:
//  1) conv1 (3x3 s=(2,1) p=1) as implicit GEMM, split-bf16 (hi+lo) MFMA, A-operand
//     staged straight from rois (NCHW fp32) with in-LDS transpose+split.  -> out1 fp32 NHWC
//  2) GroupNorm1 stats (per n,group mean/rstd)
//  3) conv2, same GEMM; GN1 normalize+ReLU applied on the fly in A-staging. -> out2 fp32 NHWC
//  4) GroupNorm2 stats; x-build: normalize+ReLU+mean over H -> x (T=128,N=64,C=256) split-bf16
//  5) gatesX = x @ Wih^T (both dirs) as split-bf16 GEMM -> fp32
//  6) BiLSTM recurrence: one block per (dir,n); fp32 Whh streamed from L2; h in LDS.
//     writes hs (T,N,512) as split-bf16
//  7) enc = hs @ emb_w^T + emb_b (split-bf16 GEMM) -> fp32
//  8) decoder: one persistent block per n, 25 steps fully in-block (attention softmax,
//     comb+ReLU, GRU, logits, log_softmax, argmax feedback), all fp32.
//
// Precision: split-bf16 GEMMs ~1e-5 rel err; LSTM/decoder fp32 -> minimizes risk of
// argmax-feedback flips. vat_b omitted (softmax shift invariant).

#include <hip/hip_runtime.h>
#include <cstdint>

typedef unsigned short u16;
typedef unsigned int   u32;
typedef __attribute__((ext_vector_type(8))) __bf16 bf16x8;
typedef __attribute__((ext_vector_type(4))) float  f32x4;

#define DEV static __device__ __forceinline__

DEV float bf2f(u16 u) { union { u32 i; float f; } v; v.i = ((u32)u) << 16; return v.f; }
DEV u16 f2bf(float f) {
  union { float f; u32 i; } v; v.f = f;
  u32 x = v.i;
  x += 0x7fffu + ((x >> 16) & 1u);   // RNE
  return (u16)(x >> 16);
}
DEV void splitf(float x, u16 &h, u16 &l) { h = f2bf(x); float r = x - bf2f(h); l = f2bf(r); }
DEV float sigm(float x) { return 1.f / (1.f + __expf(-x)); }
DEV float tanh_(float x) { float e = __expf(2.f * x); return 1.f - 2.f / (e + 1.f); }
DEV f32x4 mfma_bf16(bf16x8 a, bf16x8 b, f32x4 c) {
  return __builtin_amdgcn_mfma_f32_16x16x32_bf16(a, b, c, 0, 0, 0);
}

// ---------------------------------------------------------------- small repacks
__global__ __launch_bounds__(256) void k_repack_convw(const float* __restrict__ w,
                                                      u16* __restrict__ oh, u16* __restrict__ ol) {
  int idx = blockIdx.x * 256 + threadIdx.x;            // 256*2304
  if (idx >= 256 * 2304) return;
  int co = idx / 2304, r = idx - co * 2304;
  int seg = r >> 8, ci = r & 255;                      // k-order: (kh,kw) outer, ci inner
  float v = w[(co * 256 + ci) * 9 + seg];
  u16 h, l; splitf(v, h, l);
  oh[idx] = h; ol[idx] = l;
}

__global__ __launch_bounds__(256) void k_split(const float* __restrict__ s,
                                               u16* __restrict__ h, u16* __restrict__ l, int count) {
  int i = blockIdx.x * 256 + threadIdx.x;
  if (i < count) { u16 a, b; splitf(s[i], a, b); h[i] = a; l[i] = b; }
}

// ---------------------------------------------------------------- conv as implicit GEMM
// MODE 0: A from rois NCHW fp32 (in-LDS transpose).  MODE 1: A from out1 NHWC fp32 + GN1+ReLU.
// Tile: M=128 (one (n,hp), rows = w), N=128 (blockIdx.y selects cout half), K-step 32, K=2304.
template <int H_OUT, int H_IN, int MODE>
__global__ __launch_bounds__(256)
void k_conv_gemm(const float* __restrict__ Ain, const u16* __restrict__ Bth, const u16* __restrict__ Btl,
                 float* __restrict__ Out, const float* __restrict__ gstat,
                 const float* __restrict__ gamma, const float* __restrict__ beta) {
  __shared__ __align__(16) u16 Ash[128 * 32];
  __shared__ __align__(16) u16 Asl[128 * 32];
  __shared__ __align__(16) u16 Bsh[128 * 32];
  __shared__ __align__(16) u16 Bsl[128 * 32];
  const int tid = threadIdx.x;
  const int bx = blockIdx.x, ct = blockIdx.y;
  const int n = bx / H_OUT, hp = bx % H_OUT;
  const int wid = tid >> 6, lane = tid & 63;
  const int wr = wid >> 1, wc = wid & 1;
  const int lr = lane & 15, lk = lane >> 4;
  const int iw = tid & 127, chalf = tid >> 7;          // staging role: (w-row, 16-channel half)
  f32x4 acc[4][4] = {};
  for (int step = 0; step < 72; ++step) {
    const int seg = step >> 3, ci0 = (step & 7) << 5;
    const int kh = seg / 3, kw = seg - kh * 3;
    const int ih = 2 * hp + kh - 1;
    const int iws = iw + kw - 1;
    const bool ok = (ih >= 0) && (ih < H_IN) && (iws >= 0) && (iws < 128);
    // --- stage B (weights, K-contiguous) ---
#pragma unroll
    for (int j = 0; j < 2; ++j) {
      int chunk = j * 256 + tid;
      int row = chunk >> 2, sub = chunk & 3;
      int off = (ct * 128 + row) * 2304 + step * 32 + sub * 8;
      *(uint4*)&Bsh[chunk * 8] = *(const uint4*)&Bth[off];
      *(uint4*)&Bsl[chunk * 8] = *(const uint4*)&Btl[off];
    }
    // --- stage A (transpose + split) ---
    if constexpr (MODE == 0) {
      const float* src = Ain + (((long)(n * 256 + ci0) * H_IN + ih) * 128 + iws);
#pragma unroll
      for (int g8 = 0; g8 < 2; ++g8) {
        u32 ph[4], pl[4];
#pragma unroll
        for (int q = 0; q < 4; ++q) {
          int c = chalf * 16 + g8 * 8 + q * 2;
          float v0 = 0.f, v1 = 0.f;
          if (ok) { v0 = src[(long)c * (H_IN * 128)]; v1 = src[(long)(c + 1) * (H_IN * 128)]; }
          u16 h0, l0, h1, l1; splitf(v0, h0, l0); splitf(v1, h1, l1);
          ph[q] = (u32)h0 | ((u32)h1 << 16);
          pl[q] = (u32)l0 | ((u32)l1 << 16);
        }
        *(uint4*)&Ash[iw * 32 + chalf * 16 + g8 * 8] = make_uint4(ph[0], ph[1], ph[2], ph[3]);
        *(uint4*)&Asl[iw * 32 + chalf * 16 + g8 * 8] = make_uint4(pl[0], pl[1], pl[2], pl[3]);
      }
    } else {
      const float* src = Ain + ((((long)n * H_IN + ih) * 128 + iws) * 256 + ci0 + chalf * 16);
#pragma unroll
      for (int g8 = 0; g8 < 2; ++g8) {
        int c0 = ci0 + chalf * 16 + g8 * 8;            // all 8 channels share one GN group
        int g = c0 >> 3;
        float m = gstat[(n * 32 + g) * 2], rs = gstat[(n * 32 + g) * 2 + 1];
        float x[8] = {};
        if (ok) {
          float4 a = *(const float4*)(src + g8 * 8);
          float4 b = *(const float4*)(src + g8 * 8 + 4);
          x[0] = a.x; x[1] = a.y; x[2] = a.z; x[3] = a.w;
          x[4] = b.x; x[5] = b.y; x[6] = b.z; x[7] = b.w;
        }
        u32 ph[4], pl[4];
#pragma unroll
        for (int q = 0; q < 4; ++q) {
          int c = c0 + q * 2;
          float v0 = ok ? fmaxf((x[q * 2]     - m) * rs * gamma[c]     + beta[c],     0.f) : 0.f;
          float v1 = ok ? fmaxf((x[q * 2 + 1] - m) * rs * gamma[c + 1] + beta[c + 1], 0.f) : 0.f;
          u16 h0, l0, h1, l1; splitf(v0, h0, l0); splitf(v1, h1, l1);
          ph[q] = (u32)h0 | ((u32)h1 << 16);
          pl[q] = (u32)l0 | ((u32)l1 << 16);
        }
        *(uint4*)&Ash[iw * 32 + chalf * 16 + g8 * 8] = make_uint4(ph[0], ph[1], ph[2], ph[3]);
        *(uint4*)&Asl[iw * 32 + chalf * 16 + g8 * 8] = make_uint4(pl[0], pl[1], pl[2], pl[3]);
      }
    }
    __syncthreads();
    bf16x8 ah[4], al[4], bh[4], bl[4];
#pragma unroll
    for (int mi = 0; mi < 4; ++mi) {
      int row = wr * 64 + mi * 16 + lr;
      ah[mi] = *(const bf16x8*)&Ash[row * 32 + lk * 8];
      al[mi] = *(const bf16x8*)&Asl[row * 32 + lk * 8];
    }
#pragma unroll
    for (int ni = 0; ni < 4; ++ni) {
      int row = wc * 64 + ni * 16 + lr;
      bh[ni] = *(const bf16x8*)&Bsh[row * 32 + lk * 8];
      bl[ni] = *(const bf16x8*)&Bsl[row * 32 + lk * 8];
    }
#pragma unroll
    for (int mi = 0; mi < 4; ++mi)
#pragma unroll
      for (int ni = 0; ni < 4; ++ni) {
        f32x4 c = acc[mi][ni];
        c = mfma_bf16(al[mi], bh[ni], c);
        c = mfma_bf16(ah[mi], bl[ni], c);
        c = mfma_bf16(ah[mi], bh[ni], c);
        acc[mi][ni] = c;
      }
    __syncthreads();
  }
  // epilogue: C row -> w, C col -> cout ;  layout (m89/m91): col=lane&15, row=(lane>>4)*4+reg
#pragma unroll
  for (int mi = 0; mi < 4; ++mi)
#pragma unroll
    for (int ni = 0; ni < 4; ++ni)
#pragma unroll
      for (int r = 0; r < 4; ++r) {
        int w = wr * 64 + mi * 16 + lk * 4 + r;
        int co = ct * 128 + wc * 64 + ni * 16 + lr;
        Out[(((long)(n * H_OUT + hp)) * 128 + w) * 256 + co] = acc[mi][ni][r];
      }
}

// ---------------------------------------------------------------- plain split-bf16 GEMM
// C[m,col] = sum_k A[m,k]*Bt[col,k]  (+bias). A,Bt split-bf16 K-contiguous. out fp32.
__global__ __launch_bounds__(256)
void k_gemm_split(const u16* __restrict__ Ah, const u16* __restrict__ Al,
                  const u16* __restrict__ Bh, const u16* __restrict__ Bl,
                  float* __restrict__ outF, const float* __restrict__ bias, int K) {
  __shared__ __align__(16) u16 Ash[128 * 32];
  __shared__ __align__(16) u16 Asl[128 * 32];
  __shared__ __align__(16) u16 Bsh[128 * 32];
  __shared__ __align__(16) u16 Bsl[128 * 32];
  const int tid = threadIdx.x;
  const int m0 = blockIdx.x * 128, n0 = blockIdx.y * 128;
  const int N = gridDim.y * 128;
  const int wid = tid >> 6, lane = tid & 63;
  const int wr = wid >> 1, wc = wid & 1;
  const int lr = lane & 15, lk = lane >> 4;
  f32x4 acc[4][4] = {};
  const int steps = K >> 5;
  for (int s = 0; s < steps; ++s) {
    const int k0 = s << 5;
#pragma unroll
    for (int j = 0; j < 2; ++j) {
      int chunk = j * 256 + tid;
      int row = chunk >> 2, sub = chunk & 3;
      long aoff = (long)(m0 + row) * K + k0 + sub * 8;
      long boff = (long)(n0 + row) * K + k0 + sub * 8;
      *(uint4*)&Ash[chunk * 8] = *(const uint4*)&Ah[aoff];
      *(uint4*)&Asl[chunk * 8] = *(const uint4*)&Al[aoff];
      *(uint4*)&Bsh[chunk * 8] = *(const uint4*)&Bh[boff];
      *(uint4*)&Bsl[chunk * 8] = *(const uint4*)&Bl[boff];
    }
    __syncthreads();
    bf16x8 ah[4], al[4], bh[4], bl[4];
#pragma unroll
    for (int mi = 0; mi < 4; ++mi) {
      int row = wr * 64 + mi * 16 + lr;
      ah[mi] = *(const bf16x8*)&Ash[row * 32 + lk * 8];
      al[mi] = *(const bf16x8*)&Asl[row * 32 + lk * 8];
    }
#pragma unroll
    for (int ni = 0; ni < 4; ++ni) {
      int row = wc * 64 + ni * 16 + lr;
      bh[ni] = *(const bf16x8*)&Bsh[row * 32 + lk * 8];
      bl[ni] = *(const bf16x8*)&Bsl[row * 32 + lk * 8];
    }
#pragma unroll
    for (int mi = 0; mi < 4; ++mi)
#pragma unroll
      for (int ni = 0; ni < 4; ++ni) {
        f32x4 c = acc[mi][ni];
        c = mfma_bf16(al[mi], bh[ni], c);
        c = mfma_bf16(ah[mi], bl[ni], c);
        c = mfma_bf16(ah[mi], bh[ni], c);
        acc[mi][ni] = c;
      }
    __syncthreads();
  }
#pragma unroll
  for (int mi = 0; mi < 4; ++mi)
#pragma unroll
    for (int ni = 0; ni < 4; ++ni)
#pragma unroll
      for (int r = 0; r < 4; ++r) {
        int m = m0 + wr * 64 + mi * 16 + lk * 4 + r;
        int col = n0 + wc * 64 + ni * 16 + lr;
        float v = acc[mi][ni][r];
        if (bias) v += bias[col];
        outF[(long)m * N + col] = v;
      }
}

// ---------------------------------------------------------------- GroupNorm stats
__global__ __launch_bounds__(256)
void k_gn_stats(const float* __restrict__ y, float* __restrict__ stat, int H) {
  const int n = blockIdx.x >> 5, g = blockIdx.x & 31;
  const int tid = threadIdx.x;
  const int cnt = H * 128;
  float s = 0.f, q = 0.f;
  for (int i = tid; i < cnt; i += 256) {
    int h = i >> 7, w = i & 127;
    const float4* p = (const float4*)(y + (((long)(n * H + h) * 128 + w) * 256 + g * 8));
    float4 a = p[0], b = p[1];
    s += a.x + a.y + a.z + a.w + b.x + b.y + b.z + b.w;
    q += a.x * a.x + a.y * a.y + a.z * a.z + a.w * a.w + b.x * b.x + b.y * b.y + b.z * b.z + b.w * b.w;
  }
  __shared__ float rs_[256], rq_[256];
  rs_[tid] = s; rq_[tid] = q; __syncthreads();
  for (int off = 128; off > 0; off >>= 1) {
    if (tid < off) { rs_[tid] += rs_[tid + off]; rq_[tid] += rq_[tid + off]; }
    __syncthreads();
  }
  if (tid == 0) {
    float c = (float)(cnt * 8);
    float m = rs_[0] / c;
    float var = rq_[0] / c - m * m;
    stat[(n * 32 + g) * 2] = m;
    stat[(n * 32 + g) * 2 + 1] = rsqrtf(var + 1e-5f);
  }
}

// ---------------------------------------------------------------- GN2+ReLU+meanH -> x (split)
__global__ __launch_bounds__(256)
void k_xbuild(const float* __restrict__ out2, const float* __restrict__ stat,
              const float* __restrict__ gamma, const float* __restrict__ beta,
              u16* __restrict__ xh, u16* __restrict__ xl) {
  int idx = blockIdx.x * 256 + threadIdx.x;            // (t*64+n)*256 + c ; total 2,097,152
  int c = idx & 255;
  int n = (idx >> 8) & 63;
  int t = idx >> 14;
  int g = c >> 3;
  float m = stat[(n * 32 + g) * 2], rs = stat[(n * 32 + g) * 2 + 1];
  float ga = gamma[c], be = beta[c];
  float acc = 0.f;
#pragma unroll
  for (int h = 0; h < 4; ++h) {
    float v = out2[(((long)(n * 4 + h) * 128 + t) * 256) + c];
    acc += fmaxf((v - m) * rs * ga + be, 0.f);
  }
  acc *= 0.25f;
  u16 a, b; splitf(acc, a, b);
  xh[idx] = a; xl[idx] = b;
}

// ---------------------------------------------------------------- BiLSTM recurrence
// one block per (dir, n); thread tid owns hidden unit tid; h in LDS; Whh fp32 from d_in.
__global__ __launch_bounds__(256)
void k_lstm(const float* __restrict__ gXf, const float* __restrict__ gXb,
            const float* __restrict__ whhf, const float* __restrict__ whhb,
            const float* __restrict__ bihf, const float* __restrict__ bhhf,
            const float* __restrict__ bihb, const float* __restrict__ bhhb,
            u16* __restrict__ hsH, u16* __restrict__ hsL) {
  const int b = blockIdx.x;
  const int dir = b >> 6, n = b & 63;
  const int tid = threadIdx.x;
  const float* gX  = dir ? gXb  : gXf;
  const float* whh = dir ? whhb : whhf;
  const float* bih = dir ? bihb : bihf;
  const float* bhh = dir ? bhhb : bhhf;
  const float bi = bih[tid]       + bhh[tid];
  const float bf = bih[256 + tid] + bhh[256 + tid];
  const float bg = bih[512 + tid] + bhh[512 + tid];
  const float bo = bih[768 + tid] + bhh[768 + tid];
  const float* wi = whh + (long)tid * 256;
  const float* wf = whh + (long)(256 + tid) * 256;
  const float* wg = whh + (long)(512 + tid) * 256;
  const float* wo = whh + (long)(768 + tid) * 256;
  __shared__ float hsh[256];
  hsh[tid] = 0.f;
  float cc = 0.f;
  for (int s = 0; s < 128; ++s) {
    const int t = dir ? (127 - s) : s;
    __syncthreads();                                    // h ready for this step
    const float* gx = gX + (long)(t * 64 + n) * 1024;
    float ai = gx[tid] + bi;
    float af = gx[256 + tid] + bf;
    float ag = gx[512 + tid] + bg;
    float ao = gx[768 + tid] + bo;
    for (int k = 0; k < 256; k += 4) {
      float4 h4 = *(const float4*)&hsh[k];
      float4 w;
      w = *(const float4*)(wi + k); ai += h4.x * w.x + h4.y * w.y + h4.z * w.z + h4.w * w.w;
      w = *(const float4*)(wf + k); af += h4.x * w.x + h4.y * w.y + h4.z * w.z + h4.w * w.w;
      w = *(const float4*)(wg + k); ag += h4.x * w.x + h4.y * w.y + h4.z * w.z + h4.w * w.w;
      w = *(const float4*)(wo + k); ao += h4.x * w.x + h4.y * w.y + h4.z * w.z + h4.w * w.w;
    }
    float iv = sigm(ai), fv = sigm(af), gv = tanh_(ag), ov = sigm(ao);
    cc = fv * cc + iv * gv;
    float hv = ov * tanh_(cc);
    __syncthreads();                                    // all threads done reading old h
    hsh[tid] = hv;
    u16 hh, hl; splitf(hv, hh, hl);
    long o = (long)(t * 64 + n) * 512 + dir * 256 + tid;
    hsH[o] = hh; hsL[o] = hl;
  }
}

// ---------------------------------------------------------------- persistent decoder (per n)
__global__ __launch_bounds__(256)
void k_decoder(const float* __restrict__ enc, const float* __restrict__ att_emb,
               const float* __restrict__ comb_w, const float* __restrict__ comb_b,
               const float* __restrict__ gru_wih, const float* __restrict__ gru_whh,
               const float* __restrict__ gru_bih, const float* __restrict__ gru_bhh,
               const float* __restrict__ out_w, const float* __restrict__ out_b,
               const float* __restrict__ vat_w, float* __restrict__ dout) {
  const int n = blockIdx.x, tid = threadIdx.x;
  __shared__ float hsh[256], esh[256], ctx[256], osh[256], vsh[256];
  __shared__ float sc[128], lg[128];
  __shared__ float red[256];
  __shared__ int redi[256];
  __shared__ int inp_sh;
  hsh[tid] = 0.f;
  vsh[tid] = vat_w[tid];
  if (tid == 0) inp_sh = 0;
  __syncthreads();
  for (int step = 0; step < 25; ++step) {
    esh[tid] = att_emb[inp_sh * 256 + tid];
    // --- attention scores over T=128 (2 threads per t) ---
    {
      const int t = tid >> 1, hf = tid & 1;
      const float* ep = enc + ((t * 64 + n) * 256 + hf * 128);
      const float* hp = hsh + hf * 128;
      const float* vp = vsh + hf * 128;
      float a = 0.f;
      for (int k = 0; k < 128; ++k) a += tanh_(hp[k] + ep[k]) * vp[k];
      a += __shfl_xor(a, 1);
      if (hf == 0) sc[t] = a;                           // vat_b omitted: softmax-invariant
    }
    __syncthreads();
    // --- softmax over t ---
    red[tid] = (tid < 128) ? sc[tid] : -3.0e38f;
    __syncthreads();
    for (int off = 128; off >= 1; off >>= 1) {
      if (tid < off) red[tid] = fmaxf(red[tid], red[tid + off]);
      __syncthreads();
    }
    const float smax = red[0];
    __syncthreads();
    {
      float e = (tid < 128) ? __expf(sc[tid] - smax) : 0.f;
      if (tid < 128) sc[tid] = e;
      red[tid] = e;
    }
    __syncthreads();
    for (int off = 128; off >= 1; off >>= 1) {
      if (tid < off) red[tid] += red[tid + off];
      __syncthreads();
    }
    const float sinv = 1.f / red[0];
    __syncthreads();
    // --- context (c = tid) ---
    {
      float a = 0.f;
      for (int t = 0; t < 128; ++t) a += sc[t] * enc[(t * 64 + n) * 256 + tid];
      ctx[tid] = a * sinv;
    }
    __syncthreads();
    // --- o = relu(comb([e;ctx])) (row = tid) ---
    {
      const float* w = comb_w + (long)tid * 512;
      float a = comb_b[tid];
      for (int k = 0; k < 256; k += 4) {
        float4 wv = *(const float4*)(w + k);
        a += esh[k] * wv.x + esh[k + 1] * wv.y + esh[k + 2] * wv.z + esh[k + 3] * wv.w;
      }
      for (int k = 0; k < 256; k += 4) {
        float4 wv = *(const float4*)(w + 256 + k);
        a += ctx[k] * wv.x + ctx[k + 1] * wv.y + ctx[k + 2] * wv.z + ctx[k + 3] * wv.w;
      }
      osh[tid] = fmaxf(a, 0.f);
    }
    __syncthreads();
    // --- GRU (unit j = tid) ---
    float h2;
    {
      const float* wir = gru_wih + (long)tid * 256;
      const float* wiz = gru_wih + (long)(256 + tid) * 256;
      const float* win = gru_wih + (long)(512 + tid) * 256;
      const float* whr = gru_whh + (long)tid * 256;
      const float* whz = gru_whh + (long)(256 + tid) * 256;
      const float* whn = gru_whh + (long)(512 + tid) * 256;
      float ar = gru_bih[tid], az = gru_bih[256 + tid], an = gru_bih[512 + tid];
      float br = gru_bhh[tid], bz = gru_bhh[256 + tid], bn = gru_bhh[512 + tid];
      for (int k = 0; k < 256; k += 4) {
        float4 o4 = *(const float4*)&osh[k];
        float4 h4 = *(const float4*)&hsh[k];
        float4 w;
        w = *(const float4*)(wir + k); ar += o4.x * w.x + o4.y * w.y + o4.z * w.z + o4.w * w.w;
        w = *(const float4*)(wiz + k); az += o4.x * w.x + o4.y * w.y + o4.z * w.z + o4.w * w.w;
        w = *(const float4*)(win + k); an += o4.x * w.x + o4.y * w.y + o4.z * w.z + o4.w * w.w;
        w = *(const float4*)(whr + k); br += h4.x * w.x + h4.y * w.y + h4.z * w.z + h4.w * w.w;
        w = *(const float4*)(whz + k); bz += h4.x * w.x + h4.y * w.y + h4.z * w.z + h4.w * w.w;
        w = *(const float4*)(whn + k); bn += h4.x * w.x + h4.y * w.y + h4.z * w.z + h4.w * w.w;
      }
      float r = sigm(ar + br);
      float z = sigm(az + bz);
      float nn = tanh_(an + r * bn);
      h2 = (1.f - z) * nn + z * hsh[tid];
    }
    __syncthreads();                                    // all done reading old h
    hsh[tid] = h2;
    __syncthreads();
    // --- logits + log_softmax + argmax ---
    {
      float l = -3.0e38f;
      if (tid < 106) {
        const float* w = out_w + (long)tid * 256;
        float a = out_b[tid];
        for (int k = 0; k < 256; k += 4) {
          float4 h4 = *(const float4*)&hsh[k];
          float4 wv = *(const float4*)(w + k);
          a += h4.x * wv.x + h4.y * wv.y + h4.z * wv.z + h4.w * wv.w;
        }
        l = a; lg[tid] = a;
      }
      red[tid] = l;
      redi[tid] = (tid < 106) ? tid : 0x7FFFFFFF;
      __syncthreads();
      for (int off = 128; off >= 1; off >>= 1) {
        if (tid < off) {
          float v2 = red[tid + off]; int i2 = redi[tid + off];
          if (v2 > red[tid] || (v2 == red[tid] && i2 < redi[tid])) { red[tid] = v2; redi[tid] = i2; }
        }
        __syncthreads();
      }
      const float lmax = red[0];
      const int amax = redi[0];
      __syncthreads();
      red[tid] = (tid < 106) ? __expf(lg[tid] - lmax) : 0.f;
      __syncthreads();
      for (int off = 128; off >= 1; off >>= 1) {
        if (tid < off) red[tid] += red[tid + off];
        __syncthreads();
      }
      const float lse = lmax + __logf(red[0]);
      if (tid < 106) dout[((long)n * 25 + step) * 106 + tid] = lg[tid] - lse;
      if (tid == 0) inp_sh = amax;                      // greedy feedback
    }
    __syncthreads();
  }
}

// ---------------------------------------------------------------- launcher
extern "C" void kernel_launch(void* const* d_in, const int* in_sizes, int n_in,
                              void* d_out, int out_size, void* d_ws, size_t ws_size,
                              hipStream_t stream) {
  (void)in_sizes; (void)n_in; (void)out_size;
  const float* rois    = (const float*)d_in[0];
  const float* conv1_w = (const float*)d_in[1];
  const float* gn1_g   = (const float*)d_in[2];
  const float* gn1_b   = (const float*)d_in[3];
  const float* conv2_w = (const float*)d_in[4];
  const float* gn2_g   = (const float*)d_in[5];
  const float* gn2_b   = (const float*)d_in[6];
  const float* wih_f   = (const float*)d_in[7];
  const float* whh_f   = (const float*)d_in[8];
  const float* bih_f   = (const float*)d_in[9];
  const float* bhh_f   = (const float*)d_in[10];
  const float* wih_b   = (const float*)d_in[11];
  const float* whh_b   = (const float*)d_in[12];
  const float* bih_b   = (const float*)d_in[13];
  const float* bhh_b   = (const float*)d_in[14];
  const float* emb_w   = (const float*)d_in[15];
  const float* emb_b   = (const float*)d_in[16];
  const float* att_emb = (const float*)d_in[17];
  const float* comb_w  = (const float*)d_in[18];
  const float* comb_b  = (const float*)d_in[19];
  const float* gru_wih = (const float*)d_in[20];
  const float* gru_whh = (const float*)d_in[21];
  const float* gru_bih = (const float*)d_in[22];
  const float* gru_bhh = (const float*)d_in[23];
  const float* out_w   = (const float*)d_in[24];
  const float* out_b   = (const float*)d_in[25];
  const float* vat_w   = (const float*)d_in[26];
  // d_in[27] = vat_b: unused (softmax shift invariant)

  // workspace layout (liveness-aliased); total need = 116,424,704 B
  if (ws_size < 116424704u) return;
  char* ws = (char*)d_ws;
  float* OUT1  = (float*)(ws + 0);                     // 67,108,864  (dies after conv2)
  float* GXF   = (float*)(ws + 0);                     // 33,554,432  (written after OUT1 dead)
  float* GXB   = (float*)(ws + 33554432);              // 33,554,432
  float* OUT2  = (float*)(ws + 67108864);              // 33,554,432  (dies after xbuild)
  u16*   HSH_  = (u16*)  (ws + 67108864);              //  8,388,608  (after OUT2 dead)
  u16*   HSL_  = (u16*)  (ws + 75497472);              //  8,388,608
  float* ENC   = (float*)(ws + 83886080);              //  8,388,608
  u16*   XBH   = (u16*)  (ws + 100663296);             //  4,194,304
  u16*   XBL   = (u16*)  (ws + 104857600);             //  4,194,304
  u16*   W1TH  = (u16*)  (ws + 109051904);             //  1,179,648
  u16*   W1TL  = (u16*)  (ws + 110231552);
  u16*   W2TH  = (u16*)  (ws + 111411200);
  u16*   W2TL  = (u16*)  (ws + 112590848);
  u16*   WIHFH = (u16*)  (ws + 113770496);             //    524,288 each
  u16*   WIHFL = (u16*)  (ws + 114294784);
  u16*   WIHBH = (u16*)  (ws + 114819072);
  u16*   WIHBL = (u16*)  (ws + 115343360);
  u16*   EMBWH = (u16*)  (ws + 115867648);             //    262,144 each
  u16*   EMBWL = (u16*)  (ws + 116129792);
  float* GN1S  = (float*)(ws + 116391936);             //     16,384 each
  float* GN2S  = (float*)(ws + 116408320);

  // weight repacks / splits
  k_repack_convw<<<2304, 256, 0, stream>>>(conv1_w, W1TH, W1TL);
  k_repack_convw<<<2304, 256, 0, stream>>>(conv2_w, W2TH, W2TL);
  k_split<<<1024, 256, 0, stream>>>(wih_f, WIHFH, WIHFL, 262144);
  k_split<<<1024, 256, 0, stream>>>(wih_b, WIHBH, WIHBL, 262144);
  k_split<<<512, 256, 0, stream>>>(emb_w, EMBWH, EMBWL, 131072);

  // encoder
  k_conv_gemm<8, 16, 0><<<dim3(512, 2), 256, 0, stream>>>(rois, W1TH, W1TL, OUT1, nullptr, nullptr, nullptr);
  k_gn_stats<<<2048, 256, 0, stream>>>(OUT1, GN1S, 8);
  k_conv_gemm<4, 8, 1><<<dim3(256, 2), 256, 0, stream>>>(OUT1, W2TH, W2TL, OUT2, GN1S, gn1_g, gn1_b);
  k_gn_stats<<<2048, 256, 0, stream>>>(OUT2, GN2S, 4);
  k_xbuild<<<8192, 256, 0, stream>>>(OUT2, GN2S, gn2_g, gn2_b, XBH, XBL);

  // BiLSTM
  k_gemm_split<<<dim3(64, 8), 256, 0, stream>>>(XBH, XBL, WIHFH, WIHFL, GXF, nullptr, 256);
  k_gemm_split<<<dim3(64, 8), 256, 0, stream>>>(XBH, XBL, WIHBH, WIHBL, GXB, nullptr, 256);
  k_lstm<<<128, 256, 0, stream>>>(GXF, GXB, whh_f, whh_b, bih_f, bhh_f, bih_b, bhh_b, HSH_, HSL_);
  k_gemm_split<<<dim3(64, 2), 256, 0, stream>>>(HSH_, HSL_, EMBWH, EMBWL, ENC, emb_b, 512);

  // decoder
  k_decoder<<<64, 256, 0, stream>>>(ENC, att_emb, comb_w, comb_b, gru_wih, gru_whh,
                                    gru_bih, gru_bhh, out_w, out_b, vat_w, (float*)d_out);
}

// Round 2
// 4003.073 us; speedup vs baseline: 1.8149x; 1.8149x over previous
//
// ATTPredictor on MI355X — round 2: MFMA+LDS-resident BiLSTM with grid barrier.
//
// Changes vs round 1:
//  - k_lstm (4.4ms, VALUBusy 4%, latency-bound) replaced by k_lstm_mfma:
//    2 dirs x 16 blocks; each block owns 16 hidden units (64 gate rows), keeps its
//    Whh slice in LDS as split-bf16 (64KB, XOR-swizzled), computes gates for all
//    64 batch elems per step via split-bf16 MFMA (3 products), c in registers,
//    h double-buffered in global as split-bf16. Per-direction device-scope
//    arrive-and-wait barrier (monotonic counter), 128 steps.
//  - gatesX GEMM gets a packed epilogue [t][prow][n] so LSTM gx reads are float4.
// Everything else identical to the passing round-1 kernel.

#include <hip/hip_runtime.h>
#include <cstdint>

typedef unsigned short u16;
typedef unsigned int   u32;
typedef __attribute__((ext_vector_type(8))) __bf16 bf16x8;
typedef __attribute__((ext_vector_type(4))) float  f32x4;

#define DEV static __device__ __forceinline__

DEV float bf2f(u16 u) { union { u32 i; float f; } v; v.i = ((u32)u) << 16; return v.f; }
DEV u16 f2bf(float f) {
  union { float f; u32 i; } v; v.f = f;
  u32 x = v.i;
  x += 0x7fffu + ((x >> 16) & 1u);   // RNE
  return (u16)(x >> 16);
}
DEV void splitf(float x, u16 &h, u16 &l) { h = f2bf(x); float r = x - bf2f(h); l = f2bf(r); }
DEV float sigm(float x) { return 1.f / (1.f + __expf(-x)); }
DEV float tanh_(float x) { float e = __expf(2.f * x); return 1.f - 2.f / (e + 1.f); }
DEV f32x4 mfma_bf16(bf16x8 a, bf16x8 b, f32x4 c) {
  return __builtin_amdgcn_mfma_f32_16x16x32_bf16(a, b, c, 0, 0, 0);
}

// ---------------------------------------------------------------- small repacks
__global__ __launch_bounds__(256) void k_repack_convw(const float* __restrict__ w,
                                                      u16* __restrict__ oh, u16* __restrict__ ol) {
  int idx = blockIdx.x * 256 + threadIdx.x;            // 256*2304
  if (idx >= 256 * 2304) return;
  int co = idx / 2304, r = idx - co * 2304;
  int seg = r >> 8, ci = r & 255;                      // k-order: (kh,kw) outer, ci inner
  float v = w[(co * 256 + ci) * 9 + seg];
  u16 h, l; splitf(v, h, l);
  oh[idx] = h; ol[idx] = l;
}

__global__ __launch_bounds__(256) void k_split(const float* __restrict__ s,
                                               u16* __restrict__ h, u16* __restrict__ l, int count) {
  int i = blockIdx.x * 256 + threadIdx.x;
  if (i < count) { u16 a, b; splitf(s[i], a, b); h[i] = a; l[i] = b; }
}

// ---------------------------------------------------------------- conv as implicit GEMM
template <int H_OUT, int H_IN, int MODE>
__global__ __launch_bounds__(256)
void k_conv_gemm(const float* __restrict__ Ain, const u16* __restrict__ Bth, const u16* __restrict__ Btl,
                 float* __restrict__ Out, const float* __restrict__ gstat,
                 const float* __restrict__ gamma, const float* __restrict__ beta) {
  __shared__ __align__(16) u16 Ash[128 * 32];
  __shared__ __align__(16) u16 Asl[128 * 32];
  __shared__ __align__(16) u16 Bsh[128 * 32];
  __shared__ __align__(16) u16 Bsl[128 * 32];
  const int tid = threadIdx.x;
  const int bx = blockIdx.x, ct = blockIdx.y;
  const int n = bx / H_OUT, hp = bx % H_OUT;
  const int wid = tid >> 6, lane = tid & 63;
  const int wr = wid >> 1, wc = wid & 1;
  const int lr = lane & 15, lk = lane >> 4;
  const int iw = tid & 127, chalf = tid >> 7;
  f32x4 acc[4][4] = {};
  for (int step = 0; step < 72; ++step) {
    const int seg = step >> 3, ci0 = (step & 7) << 5;
    const int kh = seg / 3, kw = seg - kh * 3;
    const int ih = 2 * hp + kh - 1;
    const int iws = iw + kw - 1;
    const bool ok = (ih >= 0) && (ih < H_IN) && (iws >= 0) && (iws < 128);
#pragma unroll
    for (int j = 0; j < 2; ++j) {
      int chunk = j * 256 + tid;
      int row = chunk >> 2, sub = chunk & 3;
      int off = (ct * 128 + row) * 2304 + step * 32 + sub * 8;
      *(uint4*)&Bsh[chunk * 8] = *(const uint4*)&Bth[off];
      *(uint4*)&Bsl[chunk * 8] = *(const uint4*)&Btl[off];
    }
    if constexpr (MODE == 0) {
      const float* src = Ain + (((long)(n * 256 + ci0) * H_IN + ih) * 128 + iws);
#pragma unroll
      for (int g8 = 0; g8 < 2; ++g8) {
        u32 ph[4], pl[4];
#pragma unroll
        for (int q = 0; q < 4; ++q) {
          int c = chalf * 16 + g8 * 8 + q * 2;
          float v0 = 0.f, v1 = 0.f;
          if (ok) { v0 = src[(long)c * (H_IN * 128)]; v1 = src[(long)(c + 1) * (H_IN * 128)]; }
          u16 h0, l0, h1, l1; splitf(v0, h0, l0); splitf(v1, h1, l1);
          ph[q] = (u32)h0 | ((u32)h1 << 16);
          pl[q] = (u32)l0 | ((u32)l1 << 16);
        }
        *(uint4*)&Ash[iw * 32 + chalf * 16 + g8 * 8] = make_uint4(ph[0], ph[1], ph[2], ph[3]);
        *(uint4*)&Asl[iw * 32 + chalf * 16 + g8 * 8] = make_uint4(pl[0], pl[1], pl[2], pl[3]);
      }
    } else {
      const float* src = Ain + ((((long)n * H_IN + ih) * 128 + iws) * 256 + ci0 + chalf * 16);
#pragma unroll
      for (int g8 = 0; g8 < 2; ++g8) {
        int c0 = ci0 + chalf * 16 + g8 * 8;
        int g = c0 >> 3;
        float m = gstat[(n * 32 + g) * 2], rs = gstat[(n * 32 + g) * 2 + 1];
        float x[8] = {};
        if (ok) {
          float4 a = *(const float4*)(src + g8 * 8);
          float4 b = *(const float4*)(src + g8 * 8 + 4);
          x[0] = a.x; x[1] = a.y; x[2] = a.z; x[3] = a.w;
          x[4] = b.x; x[5] = b.y; x[6] = b.z; x[7] = b.w;
        }
        u32 ph[4], pl[4];
#pragma unroll
        for (int q = 0; q < 4; ++q) {
          int c = c0 + q * 2;
          float v0 = ok ? fmaxf((x[q * 2]     - m) * rs * gamma[c]     + beta[c],     0.f) : 0.f;
          float v1 = ok ? fmaxf((x[q * 2 + 1] - m) * rs * gamma[c + 1] + beta[c + 1], 0.f) : 0.f;
          u16 h0, l0, h1, l1; splitf(v0, h0, l0); splitf(v1, h1, l1);
          ph[q] = (u32)h0 | ((u32)h1 << 16);
          pl[q] = (u32)l0 | ((u32)l1 << 16);
        }
        *(uint4*)&Ash[iw * 32 + chalf * 16 + g8 * 8] = make_uint4(ph[0], ph[1], ph[2], ph[3]);
        *(uint4*)&Asl[iw * 32 + chalf * 16 + g8 * 8] = make_uint4(pl[0], pl[1], pl[2], pl[3]);
      }
    }
    __syncthreads();
    bf16x8 ah[4], al[4], bh[4], bl[4];
#pragma unroll
    for (int mi = 0; mi < 4; ++mi) {
      int row = wr * 64 + mi * 16 + lr;
      ah[mi] = *(const bf16x8*)&Ash[row * 32 + lk * 8];
      al[mi] = *(const bf16x8*)&Asl[row * 32 + lk * 8];
    }
#pragma unroll
    for (int ni = 0; ni < 4; ++ni) {
      int row = wc * 64 + ni * 16 + lr;
      bh[ni] = *(const bf16x8*)&Bsh[row * 32 + lk * 8];
      bl[ni] = *(const bf16x8*)&Bsl[row * 32 + lk * 8];
    }
#pragma unroll
    for (int mi = 0; mi < 4; ++mi)
#pragma unroll
      for (int ni = 0; ni < 4; ++ni) {
        f32x4 c = acc[mi][ni];
        c = mfma_bf16(al[mi], bh[ni], c);
        c = mfma_bf16(ah[mi], bl[ni], c);
        c = mfma_bf16(ah[mi], bh[ni], c);
        acc[mi][ni] = c;
      }
    __syncthreads();
  }
#pragma unroll
  for (int mi = 0; mi < 4; ++mi)
#pragma unroll
    for (int ni = 0; ni < 4; ++ni)
#pragma unroll
      for (int r = 0; r < 4; ++r) {
        int w = wr * 64 + mi * 16 + lk * 4 + r;
        int co = ct * 128 + wc * 64 + ni * 16 + lr;
        Out[(((long)(n * H_OUT + hp)) * 128 + w) * 256 + co] = acc[mi][ni][r];
      }
}

// ---------------------------------------------------------------- plain split-bf16 GEMM
__global__ __launch_bounds__(256)
void k_gemm_split(const u16* __restrict__ Ah, const u16* __restrict__ Al,
                  const u16* __restrict__ Bh, const u16* __restrict__ Bl,
                  float* __restrict__ outF, const float* __restrict__ bias, int K) {
  __shared__ __align__(16) u16 Ash[128 * 32];
  __shared__ __align__(16) u16 Asl[128 * 32];
  __shared__ __align__(16) u16 Bsh[128 * 32];
  __shared__ __align__(16) u16 Bsl[128 * 32];
  const int tid = threadIdx.x;
  const int m0 = blockIdx.x * 128, n0 = blockIdx.y * 128;
  const int N = gridDim.y * 128;
  const int wid = tid >> 6, lane = tid & 63;
  const int wr = wid >> 1, wc = wid & 1;
  const int lr = lane & 15, lk = lane >> 4;
  f32x4 acc[4][4] = {};
  const int steps = K >> 5;
  for (int s = 0; s < steps; ++s) {
    const int k0 = s << 5;
#pragma unroll
    for (int j = 0; j < 2; ++j) {
      int chunk = j * 256 + tid;
      int row = chunk >> 2, sub = chunk & 3;
      long aoff = (long)(m0 + row) * K + k0 + sub * 8;
      long boff = (long)(n0 + row) * K + k0 + sub * 8;
      *(uint4*)&Ash[chunk * 8] = *(const uint4*)&Ah[aoff];
      *(uint4*)&Asl[chunk * 8] = *(const uint4*)&Al[aoff];
      *(uint4*)&Bsh[chunk * 8] = *(const uint4*)&Bh[boff];
      *(uint4*)&Bsl[chunk * 8] = *(const uint4*)&Bl[boff];
    }
    __syncthreads();
    bf16x8 ah[4], al[4], bh[4], bl[4];
#pragma unroll
    for (int mi = 0; mi < 4; ++mi) {
      int row = wr * 64 + mi * 16 + lr;
      ah[mi] = *(const bf16x8*)&Ash[row * 32 + lk * 8];
      al[mi] = *(const bf16x8*)&Asl[row * 32 + lk * 8];
    }
#pragma unroll
    for (int ni = 0; ni < 4; ++ni) {
      int row = wc * 64 + ni * 16 + lr;
      bh[ni] = *(const bf16x8*)&Bsh[row * 32 + lk * 8];
      bl[ni] = *(const bf16x8*)&Bsl[row * 32 + lk * 8];
    }
#pragma unroll
    for (int mi = 0; mi < 4; ++mi)
#pragma unroll
      for (int ni = 0; ni < 4; ++ni) {
        f32x4 c = acc[mi][ni];
        c = mfma_bf16(al[mi], bh[ni], c);
        c = mfma_bf16(ah[mi], bl[ni], c);
        c = mfma_bf16(ah[mi], bh[ni], c);
        acc[mi][ni] = c;
      }
    __syncthreads();
  }
#pragma unroll
  for (int mi = 0; mi < 4; ++mi)
#pragma unroll
    for (int ni = 0; ni < 4; ++ni)
#pragma unroll
      for (int r = 0; r < 4; ++r) {
        int m = m0 + wr * 64 + mi * 16 + lk * 4 + r;
        int col = n0 + wc * 64 + ni * 16 + lr;
        float v = acc[mi][ni][r];
        if (bias) v += bias[col];
        outF[(long)m * N + col] = v;
      }
}

// ---------------------------------------------------------------- gatesX GEMM, packed epilogue
// same GEMM as above (M=8192 rows of XB, N=1024 gate rows, K=256), but writes
// gxP[t][prow][n] where prow = (u>>4)*64 + gate*16 + (u&15)  (u = col&255, gate = col>>8)
__global__ __launch_bounds__(256)
void k_gemm_gx(const u16* __restrict__ Ah, const u16* __restrict__ Al,
               const u16* __restrict__ Bh, const u16* __restrict__ Bl,
               float* __restrict__ outF) {
  __shared__ __align__(16) u16 Ash[128 * 32];
  __shared__ __align__(16) u16 Asl[128 * 32];
  __shared__ __align__(16) u16 Bsh[128 * 32];
  __shared__ __align__(16) u16 Bsl[128 * 32];
  const int tid = threadIdx.x;
  const int m0 = blockIdx.x * 128, n0 = blockIdx.y * 128;
  const int K = 256;
  const int wid = tid >> 6, lane = tid & 63;
  const int wr = wid >> 1, wc = wid & 1;
  const int lr = lane & 15, lk = lane >> 4;
  f32x4 acc[4][4] = {};
  for (int s = 0; s < 8; ++s) {
    const int k0 = s << 5;
#pragma unroll
    for (int j = 0; j < 2; ++j) {
      int chunk = j * 256 + tid;
      int row = chunk >> 2, sub = chunk & 3;
      long aoff = (long)(m0 + row) * K + k0 + sub * 8;
      long boff = (long)(n0 + row) * K + k0 + sub * 8;
      *(uint4*)&Ash[chunk * 8] = *(const uint4*)&Ah[aoff];
      *(uint4*)&Asl[chunk * 8] = *(const uint4*)&Al[aoff];
      *(uint4*)&Bsh[chunk * 8] = *(const uint4*)&Bh[boff];
      *(uint4*)&Bsl[chunk * 8] = *(const uint4*)&Bl[boff];
    }
    __syncthreads();
    bf16x8 ah[4], al[4], bh[4], bl[4];
#pragma unroll
    for (int mi = 0; mi < 4; ++mi) {
      int row = wr * 64 + mi * 16 + lr;
      ah[mi] = *(const bf16x8*)&Ash[row * 32 + lk * 8];
      al[mi] = *(const bf16x8*)&Asl[row * 32 + lk * 8];
    }
#pragma unroll
    for (int ni = 0; ni < 4; ++ni) {
      int row = wc * 64 + ni * 16 + lr;
      bh[ni] = *(const bf16x8*)&Bsh[row * 32 + lk * 8];
      bl[ni] = *(const bf16x8*)&Bsl[row * 32 + lk * 8];
    }
#pragma unroll
    for (int mi = 0; mi < 4; ++mi)
#pragma unroll
      for (int ni = 0; ni < 4; ++ni) {
        f32x4 c = acc[mi][ni];
        c = mfma_bf16(al[mi], bh[ni], c);
        c = mfma_bf16(ah[mi], bl[ni], c);
        c = mfma_bf16(ah[mi], bh[ni], c);
        acc[mi][ni] = c;
      }
    __syncthreads();
  }
  // packed epilogue: m = t*64 + n ; n = mi*16+lk*4+r (contiguous in r -> float4 store)
#pragma unroll
  for (int mi = 0; mi < 4; ++mi)
#pragma unroll
    for (int ni = 0; ni < 4; ++ni) {
      int t = blockIdx.x * 2 + wr;
      int nbase = mi * 16 + lk * 4;
      int col = n0 + wc * 64 + ni * 16 + lr;
      int gate = col >> 8, u = col & 255;
      int prow = ((u >> 4) << 6) + (gate << 4) + (u & 15);
      float4 st = make_float4(acc[mi][ni][0], acc[mi][ni][1], acc[mi][ni][2], acc[mi][ni][3]);
      *(float4*)&outF[((long)t * 1024 + prow) * 64 + nbase] = st;
    }
}

// ---------------------------------------------------------------- GroupNorm stats
__global__ __launch_bounds__(256)
void k_gn_stats(const float* __restrict__ y, float* __restrict__ stat, int H) {
  const int n = blockIdx.x >> 5, g = blockIdx.x & 31;
  const int tid = threadIdx.x;
  const int cnt = H * 128;
  float s = 0.f, q = 0.f;
  for (int i = tid; i < cnt; i += 256) {
    int h = i >> 7, w = i & 127;
    const float4* p = (const float4*)(y + (((long)(n * H + h) * 128 + w) * 256 + g * 8));
    float4 a = p[0], b = p[1];
    s += a.x + a.y + a.z + a.w + b.x + b.y + b.z + b.w;
    q += a.x * a.x + a.y * a.y + a.z * a.z + a.w * a.w + b.x * b.x + b.y * b.y + b.z * b.z + b.w * b.w;
  }
  __shared__ float rs_[256], rq_[256];
  rs_[tid] = s; rq_[tid] = q; __syncthreads();
  for (int off = 128; off > 0; off >>= 1) {
    if (tid < off) { rs_[tid] += rs_[tid + off]; rq_[tid] += rq_[tid + off]; }
    __syncthreads();
  }
  if (tid == 0) {
    float c = (float)(cnt * 8);
    float m = rs_[0] / c;
    float var = rq_[0] / c - m * m;
    stat[(n * 32 + g) * 2] = m;
    stat[(n * 32 + g) * 2 + 1] = rsqrtf(var + 1e-5f);
  }
}

// ---------------------------------------------------------------- GN2+ReLU+meanH -> x (split)
__global__ __launch_bounds__(256)
void k_xbuild(const float* __restrict__ out2, const float* __restrict__ stat,
              const float* __restrict__ gamma, const float* __restrict__ beta,
              u16* __restrict__ xh, u16* __restrict__ xl) {
  int idx = blockIdx.x * 256 + threadIdx.x;
  int c = idx & 255;
  int n = (idx >> 8) & 63;
  int t = idx >> 14;
  int g = c >> 3;
  float m = stat[(n * 32 + g) * 2], rs = stat[(n * 32 + g) * 2 + 1];
  float ga = gamma[c], be = beta[c];
  float acc = 0.f;
#pragma unroll
  for (int h = 0; h < 4; ++h) {
    float v = out2[(((long)(n * 4 + h) * 128 + t) * 256) + c];
    acc += fmaxf((v - m) * rs * ga + be, 0.f);
  }
  acc *= 0.25f;
  u16 a, b; splitf(acc, a, b);
  xh[idx] = a; xl[idx] = b;
}

// ---------------------------------------------------------------- BiLSTM via MFMA + grid barrier
// grid = 32 blocks (dir = bid>>4, b = bid&15); block owns units [16b,16b+16) of its dir.
// LDS: Whh slice split-bf16, rows r = gate*16+uu (64 rows x 256 k), XOR-swizzled.
// h double-buffered in global split-bf16 [buf][dir][n][u]; c in registers.
__global__ __launch_bounds__(256)
void k_lstm_mfma(const float* __restrict__ gxPf, const float* __restrict__ gxPb,
                 const float* __restrict__ whhf, const float* __restrict__ whhb,
                 const float* __restrict__ bihf, const float* __restrict__ bhhf,
                 const float* __restrict__ bihb, const float* __restrict__ bhhb,
                 u16* __restrict__ hHi, u16* __restrict__ hLo,
                 u16* __restrict__ hsH, u16* __restrict__ hsL,
                 int* __restrict__ bar) {
  __shared__ __align__(16) u16 WH[64 * 256];
  __shared__ __align__(16) u16 WL[64 * 256];
  const int tid = threadIdx.x;
  const int dir = blockIdx.x >> 4;
  const int b   = blockIdx.x & 15;
  const float* whh = dir ? whhb : whhf;
  const float* bih = dir ? bihb : bihf;
  const float* bhh = dir ? bhhb : bhhf;
  const float* gxP = dir ? gxPb : gxPf;
  // stage W slice (swizzled): 64 rows x 256 k, 4 floats per iter
  for (int i = tid; i < 4096; i += 256) {
    int r = i >> 6;
    int kc = (i & 63) << 2;
    int gate = r >> 4, uu = r & 15;
    const float* src = whh + ((long)(gate * 256 + b * 16 + uu)) * 256 + kc;
    float4 v = *(const float4*)src;
    u16 h0, l0, h1, l1, h2, l2, h3, l3;
    splitf(v.x, h0, l0); splitf(v.y, h1, l1); splitf(v.z, h2, l2); splitf(v.w, h3, l3);
    int byte = (r << 9) + (kc << 1);
    byte ^= (r & 7) << 4;
    *(ushort4*)((char*)WH + byte) = make_ushort4(h0, h1, h2, h3);
    *(ushort4*)((char*)WL + byte) = make_ushort4(l0, l1, l2, l3);
  }
  const int wid = tid >> 6, lane = tid & 63;
  const int lr = lane & 15, lk = lane >> 4;
  const int n0 = wid * 16;
  const int u = b * 16 + lr;
  float bias4[4];
#pragma unroll
  for (int g = 0; g < 4; ++g) {
    int row = g * 256 + u;
    bias4[g] = bih[row] + bhh[row];
  }
  float creg[4] = {0.f, 0.f, 0.f, 0.f};
  const char* WHc = (const char*)WH;
  const char* WLc = (const char*)WL;
  __syncthreads();
  for (int s = 0; s < 128; ++s) {
    const int t = dir ? (127 - s) : s;
    const int rb = s & 1, wb = rb ^ 1;
    const u16* hrH = hHi + (size_t)((rb * 2 + dir) * 64) * 256;
    const u16* hrL = hLo + (size_t)((rb * 2 + dir) * 64) * 256;
    f32x4 acc[4] = {};
#pragma unroll
    for (int ks = 0; ks < 8; ++ks) {
      bf16x8 ah = *(const bf16x8*)&hrH[(n0 + lr) * 256 + ks * 32 + lk * 8];
      bf16x8 al = *(const bf16x8*)&hrL[(n0 + lr) * 256 + ks * 32 + lk * 8];
#pragma unroll
      for (int ni = 0; ni < 4; ++ni) {
        int byte = ((ni * 16 + lr) << 9) + (ks << 6) + (lk << 4);
        byte ^= (lr & 7) << 4;
        bf16x8 bh = *(const bf16x8*)(WHc + byte);
        bf16x8 bl = *(const bf16x8*)(WLc + byte);
        f32x4 c = acc[ni];
        c = mfma_bf16(al, bh, c);
        c = mfma_bf16(ah, bl, c);
        c = mfma_bf16(ah, bh, c);
        acc[ni] = c;
      }
    }
    // epilogue: gx + bias, activations, c/h update
    float4 gx[4];
#pragma unroll
    for (int ni = 0; ni < 4; ++ni)
      gx[ni] = *(const float4*)&gxP[((long)t * 1024 + b * 64 + ni * 16 + lr) * 64 + n0 + lk * 4];
    u16* hwH = hHi + (size_t)((wb * 2 + dir) * 64) * 256;
    u16* hwL = hLo + (size_t)((wb * 2 + dir) * 64) * 256;
#pragma unroll
    for (int r = 0; r < 4; ++r) {
      float iv = sigm(acc[0][r] + ((const float*)&gx[0])[r] + bias4[0]);
      float fv = sigm(acc[1][r] + ((const float*)&gx[1])[r] + bias4[1]);
      float gv = tanh_(acc[2][r] + ((const float*)&gx[2])[r] + bias4[2]);
      float ov = sigm(acc[3][r] + ((const float*)&gx[3])[r] + bias4[3]);
      creg[r] = fv * creg[r] + iv * gv;
      float hv = ov * tanh_(creg[r]);
      u16 hh, hl; splitf(hv, hh, hl);
      int n = n0 + lk * 4 + r;
      hwH[n * 256 + u] = hh;
      hwL[n * 256 + u] = hl;
      size_t o = ((size_t)(t * 64 + n)) * 512 + dir * 256 + u;
      hsH[o] = hh; hsL[o] = hl;
    }
    // per-direction grid barrier (monotonic counter; all 32 blocks co-resident)
    __syncthreads();                                   // drains vmcnt: all h stores at L2
    if (tid == 0) {
      __hip_atomic_fetch_add(&bar[dir], 1, __ATOMIC_ACQ_REL, __HIP_MEMORY_SCOPE_AGENT);
      const int target = (s + 1) * 16;
      while (__hip_atomic_load(&bar[dir], __ATOMIC_RELAXED, __HIP_MEMORY_SCOPE_AGENT) < target)
        __builtin_amdgcn_s_sleep(1);
    }
    __syncthreads();
    __threadfence();                                   // acquire: invalidate stale h lines
  }
}

// ---------------------------------------------------------------- persistent decoder (per n)
__global__ __launch_bounds__(256)
void k_decoder(const float* __restrict__ enc, const float* __restrict__ att_emb,
               const float* __restrict__ comb_w, const float* __restrict__ comb_b,
               const float* __restrict__ gru_wih, const float* __restrict__ gru_whh,
               const float* __restrict__ gru_bih, const float* __restrict__ gru_bhh,
               const float* __restrict__ out_w, const float* __restrict__ out_b,
               const float* __restrict__ vat_w, float* __restrict__ dout) {
  const int n = blockIdx.x, tid = threadIdx.x;
  __shared__ float hsh[256], esh[256], ctx[256], osh[256], vsh[256];
  __shared__ float sc[128], lg[128];
  __shared__ float red[256];
  __shared__ int redi[256];
  __shared__ int inp_sh;
  hsh[tid] = 0.f;
  vsh[tid] = vat_w[tid];
  if (tid == 0) inp_sh = 0;
  __syncthreads();
  for (int step = 0; step < 25; ++step) {
    esh[tid] = att_emb[inp_sh * 256 + tid];
    {
      const int t = tid >> 1, hf = tid & 1;
      const float* ep = enc + ((t * 64 + n) * 256 + hf * 128);
      const float* hp = hsh + hf * 128;
      const float* vp = vsh + hf * 128;
      float a = 0.f;
      for (int k = 0; k < 128; ++k) a += tanh_(hp[k] + ep[k]) * vp[k];
      a += __shfl_xor(a, 1);
      if (hf == 0) sc[t] = a;
    }
    __syncthreads();
    red[tid] = (tid < 128) ? sc[tid] : -3.0e38f;
    __syncthreads();
    for (int off = 128; off >= 1; off >>= 1) {
      if (tid < off) red[tid] = fmaxf(red[tid], red[tid + off]);
      __syncthreads();
    }
    const float smax = red[0];
    __syncthreads();
    {
      float e = (tid < 128) ? __expf(sc[tid] - smax) : 0.f;
      if (tid < 128) sc[tid] = e;
      red[tid] = e;
    }
    __syncthreads();
    for (int off = 128; off >= 1; off >>= 1) {
      if (tid < off) red[tid] += red[tid + off];
      __syncthreads();
    }
    const float sinv = 1.f / red[0];
    __syncthreads();
    {
      float a = 0.f;
      for (int t = 0; t < 128; ++t) a += sc[t] * enc[(t * 64 + n) * 256 + tid];
      ctx[tid] = a * sinv;
    }
    __syncthreads();
    {
      const float* w = comb_w + (long)tid * 512;
      float a = comb_b[tid];
      for (int k = 0; k < 256; k += 4) {
        float4 wv = *(const float4*)(w + k);
        a += esh[k] * wv.x + esh[k + 1] * wv.y + esh[k + 2] * wv.z + esh[k + 3] * wv.w;
      }
      for (int k = 0; k < 256; k += 4) {
        float4 wv = *(const float4*)(w + 256 + k);
        a += ctx[k] * wv.x + ctx[k + 1] * wv.y + ctx[k + 2] * wv.z + ctx[k + 3] * wv.w;
      }
      osh[tid] = fmaxf(a, 0.f);
    }
    __syncthreads();
    float h2;
    {
      const float* wir = gru_wih + (long)tid * 256;
      const float* wiz = gru_wih + (long)(256 + tid) * 256;
      const float* win = gru_wih + (long)(512 + tid) * 256;
      const float* whr = gru_whh + (long)tid * 256;
      const float* whz = gru_whh + (long)(256 + tid) * 256;
      const float* whn = gru_whh + (long)(512 + tid) * 256;
      float ar = gru_bih[tid], az = gru_bih[256 + tid], an = gru_bih[512 + tid];
      float br = gru_bhh[tid], bz = gru_bhh[256 + tid], bn = gru_bhh[512 + tid];
      for (int k = 0; k < 256; k += 4) {
        float4 o4 = *(const float4*)&osh[k];
        float4 h4 = *(const float4*)&hsh[k];
        float4 w;
        w = *(const float4*)(wir + k); ar += o4.x * w.x + o4.y * w.y + o4.z * w.z + o4.w * w.w;
        w = *(const float4*)(wiz + k); az += o4.x * w.x + o4.y * w.y + o4.z * w.z + o4.w * w.w;
        w = *(const float4*)(win + k); an += o4.x * w.x + o4.y * w.y + o4.z * w.z + o4.w * w.w;
        w = *(const float4*)(whr + k); br += h4.x * w.x + h4.y * w.y + h4.z * w.z + h4.w * w.w;
        w = *(const float4*)(whz + k); bz += h4.x * w.x + h4.y * w.y + h4.z * w.z + h4.w * w.w;
        w = *(const float4*)(whn + k); bn += h4.x * w.x + h4.y * w.y + h4.z * w.z + h4.w * w.w;
      }
      float r = sigm(ar + br);
      float z = sigm(az + bz);
      float nn = tanh_(an + r * bn);
      h2 = (1.f - z) * nn + z * hsh[tid];
    }
    __syncthreads();
    hsh[tid] = h2;
    __syncthreads();
    {
      float l = -3.0e38f;
      if (tid < 106) {
        const float* w = out_w + (long)tid * 256;
        float a = out_b[tid];
        for (int k = 0; k < 256; k += 4) {
          float4 h4 = *(const float4*)&hsh[k];
          float4 wv = *(const float4*)(w + k);
          a += h4.x * wv.x + h4.y * wv.y + h4.z * wv.z + h4.w * wv.w;
        }
        l = a; lg[tid] = a;
      }
      red[tid] = l;
      redi[tid] = (tid < 106) ? tid : 0x7FFFFFFF;
      __syncthreads();
      for (int off = 128; off >= 1; off >>= 1) {
        if (tid < off) {
          float v2 = red[tid + off]; int i2 = redi[tid + off];
          if (v2 > red[tid] || (v2 == red[tid] && i2 < redi[tid])) { red[tid] = v2; redi[tid] = i2; }
        }
        __syncthreads();
      }
      const float lmax = red[0];
      const int amax = redi[0];
      __syncthreads();
      red[tid] = (tid < 106) ? __expf(lg[tid] - lmax) : 0.f;
      __syncthreads();
      for (int off = 128; off >= 1; off >>= 1) {
        if (tid < off) red[tid] += red[tid + off];
        __syncthreads();
      }
      const float lse = lmax + __logf(red[0]);
      if (tid < 106) dout[((long)n * 25 + step) * 106 + tid] = lg[tid] - lse;
      if (tid == 0) inp_sh = amax;
    }
    __syncthreads();
  }
}

// ---------------------------------------------------------------- launcher
extern "C" void kernel_launch(void* const* d_in, const int* in_sizes, int n_in,
                              void* d_out, int out_size, void* d_ws, size_t ws_size,
                              hipStream_t stream) {
  (void)in_sizes; (void)n_in; (void)out_size;
  const float* rois    = (const float*)d_in[0];
  const float* conv1_w = (const float*)d_in[1];
  const float* gn1_g   = (const float*)d_in[2];
  const float* gn1_b   = (const float*)d_in[3];
  const float* conv2_w = (const float*)d_in[4];
  const float* gn2_g   = (const float*)d_in[5];
  const float* gn2_b   = (const float*)d_in[6];
  const float* wih_f   = (const float*)d_in[7];
  const float* whh_f   = (const float*)d_in[8];
  const float* bih_f   = (const float*)d_in[9];
  const float* bhh_f   = (const float*)d_in[10];
  const float* wih_b   = (const float*)d_in[11];
  const float* whh_b   = (const float*)d_in[12];
  const float* bih_b   = (const float*)d_in[13];
  const float* bhh_b   = (const float*)d_in[14];
  const float* emb_w   = (const float*)d_in[15];
  const float* emb_b   = (const float*)d_in[16];
  const float* att_emb = (const float*)d_in[17];
  const float* comb_w  = (const float*)d_in[18];
  const float* comb_b  = (const float*)d_in[19];
  const float* gru_wih = (const float*)d_in[20];
  const float* gru_whh = (const float*)d_in[21];
  const float* gru_bih = (const float*)d_in[22];
  const float* gru_bhh = (const float*)d_in[23];
  const float* out_w   = (const float*)d_in[24];
  const float* out_b   = (const float*)d_in[25];
  const float* vat_w   = (const float*)d_in[26];

  if (ws_size < 116686864u) return;
  char* ws = (char*)d_ws;
  float* OUT1  = (float*)(ws + 0);
  float* GXF   = (float*)(ws + 0);                     // packed [t][1024][64]
  float* GXB   = (float*)(ws + 33554432);
  float* OUT2  = (float*)(ws + 67108864);
  u16*   HSH_  = (u16*)  (ws + 67108864);
  u16*   HSL_  = (u16*)  (ws + 75497472);
  float* ENC   = (float*)(ws + 83886080);
  u16*   XBH   = (u16*)  (ws + 100663296);
  u16*   XBL   = (u16*)  (ws + 104857600);
  u16*   W1TH  = (u16*)  (ws + 109051904);
  u16*   W1TL  = (u16*)  (ws + 110231552);
  u16*   W2TH  = (u16*)  (ws + 111411200);
  u16*   W2TL  = (u16*)  (ws + 112590848);
  u16*   WIHFH = (u16*)  (ws + 113770496);
  u16*   WIHFL = (u16*)  (ws + 114294784);
  u16*   WIHBH = (u16*)  (ws + 114819072);
  u16*   WIHBL = (u16*)  (ws + 115343360);
  u16*   EMBWH = (u16*)  (ws + 115867648);
  u16*   EMBWL = (u16*)  (ws + 116129792);
  float* GN1S  = (float*)(ws + 116391936);
  float* GN2S  = (float*)(ws + 116408320);
  u16*   HBUFH = (u16*)  (ws + 116424704);             // 131072 B: [2][2][64][256]
  u16*   HBUFL = (u16*)  (ws + 116555776);             // 131072 B
  int*   BAR   = (int*)  (ws + 116686848);             // 16 B

  // zero h feedback buffers + barrier counters (ws is poisoned 0xAA each call)
  hipMemsetAsync(HBUFH, 0, 131072, stream);
  hipMemsetAsync(HBUFL, 0, 131072, stream);
  hipMemsetAsync(BAR, 0, 16, stream);

  // weight repacks / splits
  k_repack_convw<<<2304, 256, 0, stream>>>(conv1_w, W1TH, W1TL);
  k_repack_convw<<<2304, 256, 0, stream>>>(conv2_w, W2TH, W2TL);
  k_split<<<1024, 256, 0, stream>>>(wih_f, WIHFH, WIHFL, 262144);
  k_split<<<1024, 256, 0, stream>>>(wih_b, WIHBH, WIHBL, 262144);
  k_split<<<512, 256, 0, stream>>>(emb_w, EMBWH, EMBWL, 131072);

  // encoder
  k_conv_gemm<8, 16, 0><<<dim3(512, 2), 256, 0, stream>>>(rois, W1TH, W1TL, OUT1, nullptr, nullptr, nullptr);
  k_gn_stats<<<2048, 256, 0, stream>>>(OUT1, GN1S, 8);
  k_conv_gemm<4, 8, 1><<<dim3(256, 2), 256, 0, stream>>>(OUT1, W2TH, W2TL, OUT2, GN1S, gn1_g, gn1_b);
  k_gn_stats<<<2048, 256, 0, stream>>>(OUT2, GN2S, 4);
  k_xbuild<<<8192, 256, 0, stream>>>(OUT2, GN2S, gn2_g, gn2_b, XBH, XBL);

  // BiLSTM
  k_gemm_gx<<<dim3(64, 8), 256, 0, stream>>>(XBH, XBL, WIHFH, WIHFL, GXF);
  k_gemm_gx<<<dim3(64, 8), 256, 0, stream>>>(XBH, XBL, WIHBH, WIHBL, GXB);
  k_lstm_mfma<<<32, 256, 0, stream>>>(GXF, GXB, whh_f, whh_b, bih_f, bhh_f, bih_b, bhh_b,
                                      HBUFH, HBUFL, HSH_, HSL_, BAR);
  k_gemm_split<<<dim3(64, 2), 256, 0, stream>>>(HSH_, HSL_, EMBWH, EMBWL, ENC, emb_b, 512);

  // decoder
  k_decoder<<<64, 256, 0, stream>>>(ENC, att_emb, comb_w, comb_b, gru_wih, gru_whh,
                                    gru_bih, gru_bhh, out_w, out_b, vat_w, (float*)d_out);
}